// Round 8
// baseline (123.376 us; speedup 1.0000x reference)
//
#include <hip/hip_runtime.h>
#include <hip/hip_bf16.h>

typedef __attribute__((ext_vector_type(4))) int i32x4;
typedef __attribute__((ext_vector_type(4))) float f32x4;

#define BM 128
#define BN 64
#define THREADS 256
#define SLOT_SZ 6144       // per wave per K-tile: A 4KB (64rx64B) + B 2KB (32rx64B)
#define WAVE_LDS 18432     // 3 slots
#define SA_OFF 73728       // f32 sa[4][128]
#define SB_OFF 75776       // f32 sb[4][64]
#define LDS_TOTAL 76800    // -> 2 blocks/CU

#define VMCNT(n) asm volatile("s_waitcnt vmcnt(" #n ")" ::: "memory")
#define LGKM0()  asm volatile("s_waitcnt lgkmcnt(0)" ::: "memory")
#define MFMAI8(a, b, c) __builtin_amdgcn_mfma_i32_16x16x64_i8((a), (b), (c), 0, 0, 0)

static __device__ inline void gload_lds16(const void* g, void* l) {
  __builtin_amdgcn_global_load_lds((__attribute__((address_space(1))) void*)g,
                                   (__attribute__((address_space(3))) void*)l,
                                   16, 0, 0);
}

// ---------------- QDQ -> i8 (2q in {0,+-1,+-2}) + f32 per-256-group scales ----------
// Exact vs reference: scale=max(absmax,1e-6); t=|x/scale|; q2 = 0 / 1 / 2.
__global__ __launch_bounds__(256) void qdq_i8(const float* __restrict__ x,
                                              signed char* __restrict__ qx,
                                              float* __restrict__ sax, int gx,
                                              const float* __restrict__ w,
                                              signed char* __restrict__ qw,
                                              float* __restrict__ sbx, int gtot) {
  int g = (blockIdx.x << 2) + (threadIdx.x >> 6);
  if (g >= gtot) return;
  const int lane = threadIdx.x & 63;
  const bool isx = (g < gx);
  const int gl = isx ? g : g - gx;
  const float* src = isx ? x : w;
  int* dst = (int*)(isx ? qx : qw);
  float* sc = isx ? sax : sbx;

  const size_t base = (size_t)gl * 256 + (size_t)lane * 4;
  float4 v = *reinterpret_cast<const float4*>(src + base);
  float amax = fmaxf(fmaxf(fabsf(v.x), fabsf(v.y)), fmaxf(fabsf(v.z), fabsf(v.w)));
#pragma unroll
  for (int off = 32; off > 0; off >>= 1)
    amax = fmaxf(amax, __shfl_xor(amax, off, 64));
  const float scale = fmaxf(amax, 1e-6f);
  float in[4] = {v.x, v.y, v.z, v.w};
  int packed = 0;
#pragma unroll
  for (int i = 0; i < 4; ++i) {
    float t = fabsf(in[i] / scale);
    int q2 = t < 0.25f ? 0 : (t < 0.75f ? 1 : 2);
    if (in[i] < 0.0f) q2 = -q2;
    packed |= (q2 & 0xff) << (i * 8);
  }
  dst[(size_t)gl * 64 + lane] = packed;
  if (lane == 0) sc[gl] = scale;
}

// ---------------- GEMM i8: BARRIER-FREE wave-private 3-slot pipeline -----------------
// Block 128x64, 4 waves of 64x32. Each wave stages ITS OWN A(64rows)+B(32cols) tile
// into a private LDS ring (no inter-wave dependency -> no barriers in the K-loop).
// Pair-line swizzle per 16-row granule (0-conflict since r3):
//   phys: line=r>>1, slot=(c16+4*(r&1))^((r>>1)&7); staging source inverse-permuted.
// Hazard discipline per wave: vmcnt(12/6/0) gates tile t; ds_reads -> lgkmcnt(0) ->
// STAGE(t+3) into the just-read slot (write-after-read closed in-order).
__global__ __launch_bounds__(THREADS, 2) void gemm_i8(
    const signed char* __restrict__ A8,  // [M,K]
    const signed char* __restrict__ B8,  // [N,K]
    const float* __restrict__ sax,       // [M*4]
    const float* __restrict__ sbx,       // [N*4]
    const float* __restrict__ bias,      // [N]
    float* __restrict__ C,               // [M,N]
    int M, int N, int K) {
  extern __shared__ char smem[];

  const int tid = threadIdx.x;
  const int lane = tid & 63;
  const int wid = tid >> 6;     // 0..3
  const int wm = wid >> 1;      // 0..1 -> 64-row strip
  const int wn = wid & 1;       // 0..1 -> 32-col strip
  const int fr = lane & 15, hi = lane >> 4;

  const int nwg = gridDim.x;
  int bid = blockIdx.x;
  if ((nwg & 7) == 0) bid = (bid & 7) * (nwg >> 3) + (bid >> 3);
  const int ntn = N / BN;
  const int tm = bid / ntn, tn = bid % ntn;
  const int m0 = tm * BM, n0 = tn * BN;

  // scales (shared, read-only after one sync)
  float* sa_lds = (float*)(smem + SA_OFF);
  float* sb_lds = (float*)(smem + SB_OFF);
#pragma unroll
  for (int p = 0; p < 2; ++p) {
    int idx = p * 256 + tid, row = idx & 127, gg = idx >> 7;
    sa_lds[gg * 128 + row] = sax[(size_t)(m0 + row) * 4 + gg];
  }
  { int row = tid & 63, gg = tid >> 6;  // 256 threads = 4 groups x 64 cols
    sb_lds[gg * 64 + row] = sbx[(size_t)(n0 + row) * 4 + gg]; }
  __syncthreads();  // the ONLY barrier

  // per-wave staging lane map (inverse pair-line swizzle, 16-row granules)
  const int u = (lane & 7) ^ ((lane >> 3) & 7);
  const int rg = 2 * (lane >> 3) + (u >> 2);   // row within granule (0..15)
  const int cByte = (u & 3) * 16;
  const size_t aRow0 = (size_t)(m0 + wm * 64 + rg) * K + cByte;
  const size_t bRow0 = (size_t)(n0 + wn * 32 + rg) * K + cByte;
  const size_t g16K = (size_t)16 * K;
  char* wbase = smem + wid * WAVE_LDS;
  const int dlane = lane * 16;

#define STAGE(s, tt) do {                                              \
    char* sp = wbase + (s) * SLOT_SZ;                                  \
    const size_t ko = (size_t)(tt) * 64;                               \
    gload_lds16(A8 + aRow0 + ko,            sp + dlane);               \
    gload_lds16(A8 + aRow0 + g16K + ko,     sp + 1024 + dlane);        \
    gload_lds16(A8 + aRow0 + 2 * g16K + ko, sp + 2048 + dlane);        \
    gload_lds16(A8 + aRow0 + 3 * g16K + ko, sp + 3072 + dlane);        \
    gload_lds16(B8 + bRow0 + ko,            sp + 4096 + dlane);        \
    gload_lds16(B8 + bRow0 + g16K + ko,     sp + 5120 + dlane);        \
  } while (0)

  // swizzled frag-read offsets (16x16x64: row=i*16+fr, 16B-chunk=hi)
  const int slot16 = ((hi + 4 * (fr & 1)) ^ (fr >> 1)) << 4;
  const int aOff = (fr >> 1) * 128 + slot16;          // + i*1024
  const int bOff = 4096 + (fr >> 1) * 128 + slot16;   // + j*1024

  f32x4 master[4][2];
  i32x4 acc[4][2];
#pragma unroll
  for (int i = 0; i < 4; ++i)
#pragma unroll
    for (int j = 0; j < 2; ++j) {
      master[i][j] = (f32x4){0.f, 0.f, 0.f, 0.f};
      acc[i][j] = (i32x4){0, 0, 0, 0};
    }

  const int T = K / 64;  // 16
  STAGE(0, 0);
  STAGE(1, 1);
  STAGE(2, 2);

  int slot = 0;
  for (int t = 0; t < T; ++t) {
    if (t < T - 2) { VMCNT(12); } else if (t == T - 2) { VMCNT(6); } else { VMCNT(0); }

    const char* sp = wbase + slot * SLOT_SZ;
    i32x4 a[4], b[2];
#pragma unroll
    for (int j = 0; j < 2; ++j) b[j] = *(const i32x4*)(sp + bOff + j * 1024);
#pragma unroll
    for (int i = 0; i < 4; ++i) a[i] = *(const i32x4*)(sp + aOff + i * 1024);
    LGKM0();                                 // reads landed in regs
    __builtin_amdgcn_sched_barrier(0);       // pin: STAGE must not hoist above reads
    if (t + 3 < T) STAGE(slot, t + 3);       // refill the slot just consumed

    __builtin_amdgcn_s_setprio(1);
#pragma unroll
    for (int i = 0; i < 4; ++i)
#pragma unroll
      for (int j = 0; j < 2; ++j)
        acc[i][j] = MFMAI8(a[i], b[j], acc[i][j]);
    __builtin_amdgcn_s_setprio(0);

    if ((t & 3) == 3) {  // exact i32 segment fold: master += sa*sb/4 * acc
      const int gI = t >> 2;
      f32x4 sav[4];
      float sbq[2];
#pragma unroll
      for (int i = 0; i < 4; ++i)
        sav[i] = *(const f32x4*)(sa_lds + gI * 128 + wm * 64 + i * 16 + hi * 4);
#pragma unroll
      for (int j = 0; j < 2; ++j)
        sbq[j] = sb_lds[gI * 64 + wn * 32 + j * 16 + fr] * 0.25f;
#pragma unroll
      for (int i = 0; i < 4; ++i)
#pragma unroll
        for (int j = 0; j < 2; ++j) {
#pragma unroll
          for (int r = 0; r < 4; ++r)
            master[i][j][r] += (float)acc[i][j][r] * sav[i][r] * sbq[j];
          acc[i][j] = (i32x4){0, 0, 0, 0};
        }
    }
    slot = (slot == 2) ? 0 : slot + 1;
  }
#undef STAGE

  // epilogue: C[row][col] = master + bias[col]
#pragma unroll
  for (int j = 0; j < 2; ++j) {
    const int col = n0 + wn * 32 + j * 16 + fr;
    const float bv = bias[col];
#pragma unroll
    for (int i = 0; i < 4; ++i) {
      const int row0 = m0 + wm * 64 + i * 16 + hi * 4;
#pragma unroll
      for (int r = 0; r < 4; ++r)
        C[(size_t)(row0 + r) * N + col] = master[i][j][r] + bv;
    }
  }
}

extern "C" void kernel_launch(void* const* d_in, const int* in_sizes, int n_in,
                              void* d_out, int out_size, void* d_ws, size_t ws_size,
                              hipStream_t stream) {
  const float* x = (const float*)d_in[0];     // [M,K]
  const float* w = (const float*)d_in[1];     // [N,K]
  const float* bias = (const float*)d_in[2];  // [N]
  float* out = (float*)d_out;

  const int MK = in_sizes[0];
  const int NK = in_sizes[1];
  const int N = in_sizes[2];
  const int K = NK / N;
  const int M = MK / K;

  signed char* qx8 = (signed char*)d_ws;           // [M,K] i8
  signed char* qw8 = qx8 + (size_t)MK;             // [N,K] i8
  float* sax = (float*)(qw8 + (size_t)NK);         // MK/256
  float* sbx = sax + (size_t)(MK / 256);           // NK/256

  const int gx = MK / 256;
  const int gtot = gx + NK / 256;
  qdq_i8<<<(gtot + 3) / 4, 256, 0, stream>>>(x, qx8, sax, gx, w, qw8, sbx, gtot);

  hipFuncSetAttribute((const void*)gemm_i8, hipFuncAttributeMaxDynamicSharedMemorySize,
                      LDS_TOTAL);
  dim3 grid((M / BM) * (N / BN));
  gemm_i8<<<grid, dim3(THREADS), LDS_TOTAL, stream>>>(qx8, qw8, sax, sbx, bias, out,
                                                      M, N, K);
}

// Round 9
// 117.312 us; speedup vs baseline: 1.0517x; 1.0517x over previous
//
#include <hip/hip_runtime.h>
#include <hip/hip_bf16.h>

typedef __attribute__((ext_vector_type(8))) __bf16 bf16x8;
typedef __attribute__((ext_vector_type(4))) float f32x4;

#define BM 256
#define BN 256
#define BK 64
#define THREADS 512
#define BUF_BYTES 65536   // per K-tile: A-lo|A-hi|B-lo|B-hi, 16KB each
#define R_ALO 0
#define R_AHI 16384
#define R_BLO 32768
#define R_BHI 49152

#define VMCNT(n) asm volatile("s_waitcnt vmcnt(" #n ")" ::: "memory")
#define LGKM(n)  asm volatile("s_waitcnt lgkmcnt(" #n ")" ::: "memory")
#define MFMA16(a, b, c) __builtin_amdgcn_mfma_f32_16x16x32_bf16((a), (b), (c), 0, 0, 0)

static __device__ inline void gload_lds16(const void* g, void* l) {
  __builtin_amdgcn_global_load_lds((__attribute__((address_space(1))) void*)g,
                                   (__attribute__((address_space(3))) void*)l,
                                   16, 0, 0);
}

// ---------------- QDQ (merged x+w): per-256-group absmax, degenerate FP4 grid --------
// scale = max(absmax,1e-6); q in {0,+-0.5,+-1}; out = bf16(q*scale)
__global__ __launch_bounds__(256) void qdq2(const float* __restrict__ x,
                                            __hip_bfloat16* __restrict__ qx, int gx,
                                            const float* __restrict__ w,
                                            __hip_bfloat16* __restrict__ qw, int gtot) {
  int g = (blockIdx.x << 2) + (threadIdx.x >> 6);
  if (g >= gtot) return;
  const int lane = threadIdx.x & 63;
  const float* src = (g < gx) ? x : w;
  __hip_bfloat16* dst = (g < gx) ? qx : qw;
  const size_t base = (size_t)(g < gx ? g : g - gx) * 256 + (size_t)lane * 4;
  float4 v = *reinterpret_cast<const float4*>(src + base);
  float amax = fmaxf(fmaxf(fabsf(v.x), fabsf(v.y)), fmaxf(fabsf(v.z), fabsf(v.w)));
#pragma unroll
  for (int off = 32; off > 0; off >>= 1)
    amax = fmaxf(amax, __shfl_xor(amax, off, 64));
  float scale = fmaxf(amax, 1e-6f);
  float in[4] = {v.x, v.y, v.z, v.w};
  union { ushort4 u4; __hip_bfloat16 h[4]; } o;
#pragma unroll
  for (int i = 0; i < 4; ++i) {
    float t = fabsf(in[i] / scale);
    float q = t < 0.25f ? 0.0f : (t < 0.75f ? 0.5f : 1.0f);
    o.h[i] = __float2bfloat16(copysignf(q, in[i]) * scale);
  }
  *reinterpret_cast<ushort4*>(dst + base) = o.u4;
}

// ---------------- GEMM 256x256, 8 waves, m201-style 4-phase rolling pipeline ---------
// Phases per K-tile t (P0..P3 compute quadrants (i-lo,k0)(i-hi,k0)(i-lo,k1)(i-hi,k1)):
//   each phase ISSUES the NEXT phase's ds_reads, then {stage}{vmcnt} -> barrier ->
//   lgkm(reads-issued-this-phase) [drains PREVIOUS phase's reads] -> 16 MFMA.
// Staging (into the CURRENT buffer, half-granular, >=1 barrier after last read-issue):
//   P2: A-lo/B-lo/B-hi(t+2) [6 loads] + VMCNT(8);  P3: A-hi(t+2) [2 loads] + VMCNT(8).
// vmcnt ledger: at P2, outstanding-after = P3(t-1)2 + P2(t)6 = 8 -> older all landed
// (covers P3's reads of tile t+1); at P3 likewise covers P0(t+1)'s A-hi read. Tail:
// t=T-2 -> P2 VMCNT(2), P3 VMCNT(0); t=T-1 none.
__global__ __launch_bounds__(THREADS, 2) void gemm256(
    const __hip_bfloat16* __restrict__ A,  // [M,K]
    const __hip_bfloat16* __restrict__ B,  // [N,K]
    const float* __restrict__ bias,        // [N]
    float* __restrict__ C,                 // [M,N]
    int M, int N, int K) {
  extern __shared__ char smem[];

  const int tid = threadIdx.x;
  const int lane = tid & 63;
  const int wid = tid >> 6;
  const int wm = wid >> 2;   // A half (0 = rows 0-127)
  const int wn = wid & 3;    // 64-col strip; B half = wn>>1
  const int fr = lane & 15;
  const int hi = lane >> 4;

  const int nwg = gridDim.x;
  int bid = blockIdx.x;
  if ((nwg & 7) == 0) bid = (bid & 7) * (nwg >> 3) + (bid >> 3);
  const int ntn = N / BN;
  const int tm = bid / ntn, tn = bid % ntn;
  const int m0 = tm * BM, n0 = tn * BN;

  // staging source map (inverse of chunk-XOR swizzle; verified r4, 0 conflicts)
  const int r_st = tid >> 3;
  const size_t c_st8 = (size_t)(((tid & 7) ^ ((tid >> 3) & 7)) << 3);
  const size_t src_off = (size_t)r_st * K + c_st8;
  const size_t k64 = (size_t)K * 64;
  const __hip_bfloat16* Alo_p = A + (size_t)m0 * K;
  const __hip_bfloat16* Ahi_p = A + (size_t)(m0 + 128) * K;
  const __hip_bfloat16* Blo_p = B + (size_t)n0 * K;
  const __hip_bfloat16* Bhi_p = B + (size_t)(n0 + 128) * K;
  const int d16 = tid * 16;

#define STAGE_HALF(bufi, regOff, gbase, tt) do {                        \
    char* bb = smem + (size_t)(bufi) * BUF_BYTES + (regOff);            \
    const __hip_bfloat16* gp = (gbase) + src_off + (size_t)(tt) * BK;   \
    gload_lds16(gp, bb + d16);                                          \
    gload_lds16(gp + k64, bb + 8192 + d16);                             \
  } while (0)

  // swizzled read offsets (r4-verified): row r, chunk c -> byte r*128 + (c^(r&7))*16
  const int sw0 = ((hi ^ (fr & 7)) << 4);
  const int sw1 = (((4 + hi) ^ (fr & 7)) << 4);
  const int aB = wm * 16384 + fr * 128;                                  // + i*2048
  const int bB = R_BLO + (wn >> 1) * 16384 + (wn & 1) * 8192 + fr * 128; // + j*2048

  f32x4 acc[8][4];
#pragma unroll
  for (int i = 0; i < 8; ++i)
#pragma unroll
    for (int j = 0; j < 4; ++j) acc[i][j] = (f32x4){0.f, 0.f, 0.f, 0.f};

  const int T = K / BK;  // 16

  // prologue: tiles 0 and 1 fully staged (16 loads); gate tile0; pre-read P0(0) frags
  STAGE_HALF(0, R_ALO, Alo_p, 0);
  STAGE_HALF(0, R_BLO, Blo_p, 0);
  STAGE_HALF(0, R_BHI, Bhi_p, 0);
  STAGE_HALF(0, R_AHI, Ahi_p, 0);
  STAGE_HALF(1, R_ALO, Alo_p, 1);
  STAGE_HALF(1, R_BLO, Blo_p, 1);
  STAGE_HALF(1, R_BHI, Bhi_p, 1);
  STAGE_HALF(1, R_AHI, Ahi_p, 1);
  VMCNT(8);
  __builtin_amdgcn_s_barrier();

  bf16x8 aE[4], aO[4], b0[4], b1[4];
  {
    const char* cb = smem;  // tile 0, buf 0
#pragma unroll
    for (int i = 0; i < 4; ++i) aE[i] = *(const bf16x8*)(cb + aB + i * 2048 + sw0);
#pragma unroll
    for (int j = 0; j < 4; ++j) b0[j] = *(const bf16x8*)(cb + bB + j * 2048 + sw0);
  }

  for (int t = 0; t < T; ++t) {
    const char* cur = smem + (size_t)(t & 1) * BUF_BYTES;
    const char* nxt = smem + (size_t)((t + 1) & 1) * BUF_BYTES;

    // ---- P0: compute (i-lo, k0); issue reads for P1 (a i-hi k0) ----
#pragma unroll
    for (int i = 0; i < 4; ++i) aO[i] = *(const bf16x8*)(cur + aB + (i + 4) * 2048 + sw0);
    __builtin_amdgcn_s_barrier();
    LGKM(4);
    __builtin_amdgcn_s_setprio(1);
#pragma unroll
    for (int i = 0; i < 4; ++i)
#pragma unroll
      for (int j = 0; j < 4; ++j)
        acc[i][j] = MFMA16(aE[i], b0[j], acc[i][j]);
    __builtin_amdgcn_s_setprio(0);

    // ---- P1: compute (i-hi, k0); issue reads for P2 (a i-lo k1, b k1) ----
#pragma unroll
    for (int i = 0; i < 4; ++i) aE[i] = *(const bf16x8*)(cur + aB + i * 2048 + sw1);
#pragma unroll
    for (int j = 0; j < 4; ++j) b1[j] = *(const bf16x8*)(cur + bB + j * 2048 + sw1);
    __builtin_amdgcn_s_barrier();
    LGKM(8);
    __builtin_amdgcn_s_setprio(1);
#pragma unroll
    for (int i = 0; i < 4; ++i)
#pragma unroll
      for (int j = 0; j < 4; ++j)
        acc[i + 4][j] = MFMA16(aO[i], b0[j], acc[i + 4][j]);
    __builtin_amdgcn_s_setprio(0);

    // ---- P2: compute (i-lo, k1); issue reads for P3 (a i-hi k1); stage 3 halves ----
#pragma unroll
    for (int i = 0; i < 4; ++i) aO[i] = *(const bf16x8*)(cur + aB + (i + 4) * 2048 + sw1);
    if (t + 2 < T) {
      STAGE_HALF(t & 1, R_ALO, Alo_p, t + 2);
      STAGE_HALF(t & 1, R_BLO, Blo_p, t + 2);
      STAGE_HALF(t & 1, R_BHI, Bhi_p, t + 2);
      VMCNT(8);
    } else if (t + 1 < T) {
      VMCNT(2);
    }
    __builtin_amdgcn_s_barrier();
    LGKM(4);
    __builtin_amdgcn_s_setprio(1);
#pragma unroll
    for (int i = 0; i < 4; ++i)
#pragma unroll
      for (int j = 0; j < 4; ++j)
        acc[i][j] = MFMA16(aE[i], b1[j], acc[i][j]);
    __builtin_amdgcn_s_setprio(0);

    // ---- P3: compute (i-hi, k1); issue reads for P0(t+1); stage A-hi(t+2) ----
    if (t + 1 < T) {
#pragma unroll
      for (int i = 0; i < 4; ++i) aE[i] = *(const bf16x8*)(nxt + aB + i * 2048 + sw0);
#pragma unroll
      for (int j = 0; j < 4; ++j) b0[j] = *(const bf16x8*)(nxt + bB + j * 2048 + sw0);
    }
    if (t + 2 < T) {
      STAGE_HALF(t & 1, R_AHI, Ahi_p, t + 2);
      VMCNT(8);
    } else if (t + 1 < T) {
      VMCNT(0);
    }
    __builtin_amdgcn_s_barrier();
    if (t + 1 < T) { LGKM(8); } else { LGKM(0); }
    __builtin_amdgcn_s_setprio(1);
#pragma unroll
    for (int i = 0; i < 4; ++i)
#pragma unroll
      for (int j = 0; j < 4; ++j)
        acc[i + 4][j] = MFMA16(aO[i], b1[j], acc[i + 4][j]);
    __builtin_amdgcn_s_setprio(0);
  }
#undef STAGE_HALF

  // epilogue: C[row][col] = acc + bias[col]  (r4-verified mapping)
#pragma unroll
  for (int j = 0; j < 4; ++j) {
    const int col = n0 + wn * 64 + j * 16 + fr;
    const float bv = bias[col];
#pragma unroll
    for (int i = 0; i < 8; ++i) {
      const int row0 = m0 + wm * 128 + i * 16 + hi * 4;
#pragma unroll
      for (int r = 0; r < 4; ++r)
        C[(size_t)(row0 + r) * N + col] = acc[i][j][r] + bv;
    }
  }
}

extern "C" void kernel_launch(void* const* d_in, const int* in_sizes, int n_in,
                              void* d_out, int out_size, void* d_ws, size_t ws_size,
                              hipStream_t stream) {
  const float* x = (const float*)d_in[0];     // [M,K]
  const float* w = (const float*)d_in[1];     // [N,K]
  const float* bias = (const float*)d_in[2];  // [N]
  float* out = (float*)d_out;

  const int MK = in_sizes[0];
  const int NK = in_sizes[1];
  const int N = in_sizes[2];
  const int K = NK / N;
  const int M = MK / K;

  __hip_bfloat16* qx = (__hip_bfloat16*)d_ws;
  __hip_bfloat16* qw = qx + (size_t)MK;

  const int gx = MK / 256;
  const int gtot = gx + NK / 256;
  qdq2<<<(gtot + 3) / 4, 256, 0, stream>>>(x, qx, gx, w, qw, gtot);

  hipFuncSetAttribute((const void*)gemm256, hipFuncAttributeMaxDynamicSharedMemorySize,
                      2 * BUF_BYTES);
  dim3 grid((M / BM) * (N / BN));
  gemm256<<<grid, dim3(THREADS), 2 * BUF_BYTES, stream>>>(qx, qw, bias, out, M, N, K);
}

// Round 10
// 86.571 us; speedup vs baseline: 1.4251x; 1.3551x over previous
//
#include <hip/hip_runtime.h>
#include <hip/hip_bf16.h>

typedef __attribute__((ext_vector_type(4))) int i32x4;
typedef __attribute__((ext_vector_type(8))) int i32x8;
typedef __attribute__((ext_vector_type(4))) float f32x4;
typedef __attribute__((ext_vector_type(16))) float f32x16;

#define BM 256
#define BN 128
#define THREADS 512
#define STB 24576          // stage-tile: A 256r x 64B (16KB) + B 128r x 64B (8KB)
#define SA_OFF 73728       // f32 sa[4][256]
#define SB_OFF 77824       // f32 sb[4][128]
#define LDS_TOTAL 79872    // 78 KB -> 2 blocks/CU

#define VMCNT(n) asm volatile("s_waitcnt vmcnt(" #n ")" ::: "memory")

static __device__ inline void gload_lds16(const void* g, void* l) {
  __builtin_amdgcn_global_load_lds((__attribute__((address_space(1))) void*)g,
                                   (__attribute__((address_space(3))) void*)l,
                                   16, 0, 0);
}

// ---------------- QDQ -> packed E2M1 fp4 (value q in {0,+-0.5,+-1}) + f32 scales ----
// nibble: 0->0x0, 0.5->0x1, 1.0->0x2, sign->bit3. Low nibble = lower element index.
__global__ __launch_bounds__(256) void qdq_fp4(const float* __restrict__ x,
                                               unsigned short* __restrict__ qx,
                                               float* __restrict__ sax, int gx,
                                               const float* __restrict__ w,
                                               unsigned short* __restrict__ qw,
                                               float* __restrict__ sbx, int gtot) {
  int g = (blockIdx.x << 2) + (threadIdx.x >> 6);
  if (g >= gtot) return;
  const int lane = threadIdx.x & 63;
  const bool isx = (g < gx);
  const int gl = isx ? g : g - gx;
  const float* src = isx ? x : w;
  unsigned short* dst = isx ? qx : qw;
  float* sc = isx ? sax : sbx;

  const size_t base = (size_t)gl * 256 + (size_t)lane * 4;
  float4 v = *reinterpret_cast<const float4*>(src + base);
  float amax = fmaxf(fmaxf(fabsf(v.x), fabsf(v.y)), fmaxf(fabsf(v.z), fabsf(v.w)));
#pragma unroll
  for (int off = 32; off > 0; off >>= 1)
    amax = fmaxf(amax, __shfl_xor(amax, off, 64));
  const float scale = fmaxf(amax, 1e-6f);
  float in[4] = {v.x, v.y, v.z, v.w};
  unsigned enc = 0;
#pragma unroll
  for (int i = 0; i < 4; ++i) {
    float t = fabsf(in[i] / scale);
    unsigned q = t < 0.25f ? 0u : (t < 0.75f ? 1u : 2u);   // E2M1: 0 / 0.5 / 1.0
    if (in[i] < 0.0f) q |= 8u;
    enc |= q << (4 * i);
  }
  dst[(size_t)gl * 64 + lane] = (unsigned short)enc;       // 4 nibbles = 2 bytes
  if (lane == 0) sc[gl] = scale;
}

// ---------------- GEMM fp4: 8 waves x (64x64), 3-slot ring, 2 blocks/CU --------------
// mfma_scale_f32_32x32x64_f8f6f4, FMT=4 (fp4), MX scale byte = 127 (2^0 = 1.0):
// acc = exact sum of q_a*q_b per 256-group segment; fold master += acc*sa*sb.
// LDS slot: A[256r][64B] @0, B[128r][64B] @16384; pair-line swizzle (0-conflict r3+):
//   byte(r,c16) = (r>>1)*128 + ((c16 + 4*(r&1)) ^ ((r>>1)&7))*16
// Ring: slot = st%3; STAGE(st+2) post-barrier overwrites slot of st-1 (reads done).
// vmcnt gate at top of st: 3 newest (st+1's stage) may be outstanding -> VMCNT(3).
__global__ __launch_bounds__(THREADS, 2) void gemm_fp4(
    const unsigned char* __restrict__ A4,  // [M][K/2]
    const unsigned char* __restrict__ B4,  // [N][K/2]
    const float* __restrict__ sax,         // [M*4]
    const float* __restrict__ sbx,         // [N*4]
    const float* __restrict__ bias,        // [N]
    float* __restrict__ C,                 // [M,N]
    int M, int N, int K) {
  extern __shared__ char smem[];

  const int tid = threadIdx.x;
  const int lane = tid & 63;
  const int wid = tid >> 6;      // 0..7
  const int wrow = wid >> 1;     // 0..3 -> 64-row strip of 256
  const int wcol = wid & 1;      // 0..1 -> 64-col strip of 128
  const int l31 = lane & 31;
  const int hi2 = lane >> 5;     // k-half within 64

  const int nwg = gridDim.x;
  int bid = blockIdx.x;
  if ((nwg & 7) == 0) bid = (bid & 7) * (nwg >> 3) + (bid >> 3);
  const int ntn = N / BN;
  const int tm = bid / ntn, tn = bid % ntn;
  const int m0 = tm * BM, n0 = tn * BN;

  // scales
  float* sa_lds = (float*)(smem + SA_OFF);
  float* sb_lds = (float*)(smem + SB_OFF);
#pragma unroll
  for (int p = 0; p < 2; ++p) {
    int idx = p * 512 + tid, row = idx & 255, gg = idx >> 8;
    sa_lds[gg * 256 + row] = sax[(size_t)(m0 + row) * 4 + gg];
  }
  { int row = tid & 127, gg = (tid >> 7) & 3;
    sb_lds[gg * 128 + row] = sbx[(size_t)(n0 + row) * 4 + gg]; }
  __syncthreads();

  // staging source map (inverse pair-line swizzle; verbatim r5/r7, measured 0-conflict)
  const int u = (tid & 7) ^ ((tid >> 3) & 7);
  const int rr = 2 * (tid >> 3) + (u >> 2);   // 0..127
  const int cBy = (u & 3) * 16;
  const int Kb = K >> 1;                       // bytes per row
  const size_t srcA = (size_t)(m0 + rr) * Kb + cBy;
  const size_t srcB = (size_t)(n0 + rr) * Kb + cBy;
  const size_t aRowStep = (size_t)128 * Kb;
  const int d16 = tid * 16;

#define STAGE(slot, st) do {                                          \
    char* bb = smem + (slot) * STB;                                   \
    const unsigned char* ga = A4 + srcA + (size_t)(st) * 64;          \
    gload_lds16(ga,            bb + d16);                             \
    gload_lds16(ga + aRowStep, bb + 8192 + d16);                      \
    gload_lds16(B4 + srcB + (size_t)(st) * 64, bb + 16384 + d16);     \
  } while (0)

  // fragment read addresses (8 loop-invariant ints): frag (i|j), k-step s
  int aAddr[2][2], bAddr[2][2];
#pragma unroll
  for (int i = 0; i < 2; ++i) {
    const int r = wrow * 64 + i * 32 + l31;
#pragma unroll
    for (int s = 0; s < 2; ++s) {
      const int c16 = s * 2 + hi2;
      aAddr[i][s] = (r >> 1) * 128 + (((c16 + 4 * (r & 1)) ^ ((r >> 1) & 7)) << 4);
    }
  }
#pragma unroll
  for (int j = 0; j < 2; ++j) {
    const int r = wcol * 64 + j * 32 + l31;
#pragma unroll
    for (int s = 0; s < 2; ++s) {
      const int c16 = s * 2 + hi2;
      bAddr[j][s] = 16384 + (r >> 1) * 128 + (((c16 + 4 * (r & 1)) ^ ((r >> 1) & 7)) << 4);
    }
  }

  f32x16 acc[2][2], mst[2][2];
#pragma unroll
  for (int i = 0; i < 2; ++i)
#pragma unroll
    for (int j = 0; j < 2; ++j) {
#pragma unroll
      for (int e = 0; e < 16; ++e) { acc[i][j][e] = 0.f; mst[i][j][e] = 0.f; }
    }

  int scE8M0 = 127;  // 2^0 = 1.0 (variable, not inline-const-illegal literal)

  const int ST = K / 128;  // 8 stage-tiles
  STAGE(0, 0);
  STAGE(1, 1);

  for (int st = 0; st < ST; ++st) {
    if (st < ST - 1) { VMCNT(3); } else { VMCNT(0); }
    __builtin_amdgcn_s_barrier();
    if (st + 2 < ST) STAGE((st + 2) % 3, st + 2);

    const char* sp = smem + (st % 3) * STB;
#pragma unroll
    for (int s = 0; s < 2; ++s) {
      i32x8 av[2], bv[2];
#pragma unroll
      for (int i = 0; i < 2; ++i) {
        i32x4 t = *(const i32x4*)(sp + aAddr[i][s]);
        av[i] = (i32x8){t[0], t[1], t[2], t[3], 0, 0, 0, 0};
      }
#pragma unroll
      for (int j = 0; j < 2; ++j) {
        i32x4 t = *(const i32x4*)(sp + bAddr[j][s]);
        bv[j] = (i32x8){t[0], t[1], t[2], t[3], 0, 0, 0, 0};
      }
      __builtin_amdgcn_s_setprio(1);
#pragma unroll
      for (int i = 0; i < 2; ++i)
#pragma unroll
        for (int j = 0; j < 2; ++j)
          acc[i][j] = __builtin_amdgcn_mfma_scale_f32_32x32x64_f8f6f4(
              av[i], bv[j], acc[i][j], 4, 4, 0, scE8M0, 0, scE8M0);
      __builtin_amdgcn_s_setprio(0);
    }

    if (st & 1) {  // fold group g = st>>1: master += acc * sa[row] * sb[col]
      const int g = st >> 1;
#pragma unroll
      for (int j = 0; j < 2; ++j) {
        const float sbv = sb_lds[g * 128 + wcol * 64 + j * 32 + l31];
#pragma unroll
        for (int i = 0; i < 2; ++i) {
#pragma unroll
          for (int q = 0; q < 4; ++q) {
            f32x4 sav = *(const f32x4*)(sa_lds + g * 256 + wrow * 64 + i * 32 +
                                        q * 8 + hi2 * 4);
#pragma unroll
            for (int r = 0; r < 4; ++r)
              mst[i][j][q * 4 + r] += acc[i][j][q * 4 + r] * sav[r] * sbv;
          }
        }
      }
#pragma unroll
      for (int i = 0; i < 2; ++i)
#pragma unroll
        for (int j = 0; j < 2; ++j)
#pragma unroll
          for (int e = 0; e < 16; ++e) acc[i][j][e] = 0.f;
    }
  }
#undef STAGE

  // epilogue: C/D 32x32 map (m74/m101): col = l31, row = (e&3) + 8*(e>>2) + 4*hi2
#pragma unroll
  for (int j = 0; j < 2; ++j) {
    const int col = n0 + wcol * 64 + j * 32 + l31;
    const float bv = bias[col];
#pragma unroll
    for (int i = 0; i < 2; ++i) {
      const int rbase = m0 + wrow * 64 + i * 32 + hi2 * 4;
#pragma unroll
      for (int q = 0; q < 4; ++q)
#pragma unroll
        for (int r = 0; r < 4; ++r)
          C[(size_t)(rbase + q * 8 + r) * N + col] = mst[i][j][q * 4 + r] + bv;
    }
  }
}

extern "C" void kernel_launch(void* const* d_in, const int* in_sizes, int n_in,
                              void* d_out, int out_size, void* d_ws, size_t ws_size,
                              hipStream_t stream) {
  const float* x = (const float*)d_in[0];     // [M,K]
  const float* w = (const float*)d_in[1];     // [N,K]
  const float* bias = (const float*)d_in[2];  // [N]
  float* out = (float*)d_out;

  const int MK = in_sizes[0];
  const int NK = in_sizes[1];
  const int N = in_sizes[2];
  const int K = NK / N;
  const int M = MK / K;

  unsigned char* qx4 = (unsigned char*)d_ws;            // M*K/2 bytes
  unsigned char* qw4 = qx4 + (size_t)MK / 2;            // N*K/2 bytes
  float* sax = (float*)(qw4 + (size_t)NK / 2);          // MK/256 f32
  float* sbx = sax + (size_t)(MK / 256);                // NK/256 f32

  const int gx = MK / 256;
  const int gtot = gx + NK / 256;
  qdq_fp4<<<(gtot + 3) / 4, 256, 0, stream>>>(x, (unsigned short*)qx4, sax, gx,
                                              w, (unsigned short*)qw4, sbx, gtot);

  hipFuncSetAttribute((const void*)gemm_fp4, hipFuncAttributeMaxDynamicSharedMemorySize,
                      LDS_TOTAL);
  dim3 grid((M / BM) * (N / BN));
  gemm_fp4<<<grid, dim3(THREADS), LDS_TOTAL, stream>>>(qx4, qw4, sax, sbx, bias, out,
                                                       M, N, K);
}